// Round 1
// baseline (876.618 us; speedup 1.0000x reference)
//
#include <hip/hip_runtime.h>

#define S_LEN  1024
#define DMODEL 1024
#define NHEAD  16
#define DHEAD  64
#define MROWS  8192   // 8 sequences * 1024
#define HIDDIM 4096
#define WINR   128

typedef __attribute__((ext_vector_type(8))) short bf16x8;
typedef __attribute__((ext_vector_type(4))) float f32x4;

__device__ __forceinline__ float bf2f(unsigned short u){ return __uint_as_float(((unsigned)u) << 16); }
__device__ __forceinline__ unsigned short f2bf(float f){
  unsigned u = __float_as_uint(f);
  u += 0x7FFFu + ((u >> 16) & 1u);
  return (unsigned short)(u >> 16);
}

// ---------------- weight transpose: in f32 [R][C] -> out bf16 [C][R] ----------------
__global__ __launch_bounds__(256) void transpose_w(const float* __restrict__ in,
                                                   unsigned short* __restrict__ out,
                                                   int R, int C){
  __shared__ float tile[32][33];
  const int c0 = blockIdx.x * 32;
  const int r0 = blockIdx.y * 32;
  const int tx = threadIdx.x & 31;
  const int ty = threadIdx.x >> 5;   // 0..7
  #pragma unroll
  for (int i = 0; i < 32; i += 8)
    tile[ty + i][tx] = in[(size_t)(r0 + ty + i) * C + c0 + tx];
  __syncthreads();
  #pragma unroll
  for (int i = 0; i < 32; i += 8)
    out[(size_t)(c0 + ty + i) * R + r0 + tx] = f2bf(tile[tx][ty + i]);
}

// ---------------- LayerNorm: row per block, 4 source pointers (2048 rows each) -------
__global__ __launch_bounds__(256) void ln_kernel(const float* __restrict__ s0, const float* __restrict__ s1,
                                                 const float* __restrict__ s2, const float* __restrict__ s3,
                                                 const float* __restrict__ g, const float* __restrict__ b,
                                                 unsigned short* __restrict__ out){
  const int row = blockIdx.x;
  const int t = threadIdx.x;
  const float* src = (row < 2048) ? s0 : (row < 4096) ? s1 : (row < 6144) ? s2 : s3;
  const float* x = src + (size_t)(row & 2047) * DMODEL;
  float4 v = *(const float4*)&x[t * 4];
  float sum  = v.x + v.y + v.z + v.w;
  float ssum = v.x*v.x + v.y*v.y + v.z*v.z + v.w*v.w;
  #pragma unroll
  for (int o = 32; o > 0; o >>= 1){
    sum  += __shfl_down(sum, o);
    ssum += __shfl_down(ssum, o);
  }
  __shared__ float red[8];
  if ((t & 63) == 0){ red[t >> 6] = sum; red[4 + (t >> 6)] = ssum; }
  __syncthreads();
  sum  = red[0] + red[1] + red[2] + red[3];
  ssum = red[4] + red[5] + red[6] + red[7];
  const float mu  = sum * (1.f / DMODEL);
  const float var = ssum * (1.f / DMODEL) - mu * mu;
  const float rs  = rsqrtf(var + 1e-5f);
  float4 gg = *(const float4*)&g[t * 4];
  float4 bb = *(const float4*)&b[t * 4];
  ushort4 o;
  o.x = f2bf((v.x - mu) * rs * gg.x + bb.x);
  o.y = f2bf((v.y - mu) * rs * gg.y + bb.y);
  o.z = f2bf((v.z - mu) * rs * gg.z + bb.z);
  o.w = f2bf((v.w - mu) * rs * gg.w + bb.w);
  *(ushort4*)&out[(size_t)row * DMODEL + t * 4] = o;
}

// ---------------- banded flash attention (online softmax, f32 VALU) ------------------
// grid: n(8) * head(16) * qtile(16); block 256 = 4 waves, wave -> 16 q rows,
// 4 lanes per q row (each owns 16 of 64 dims)
__global__ __launch_bounds__(256) void attn_kernel(const unsigned short* __restrict__ qh,
                                                   const unsigned short* __restrict__ kh,
                                                   const unsigned short* __restrict__ vh,
                                                   unsigned short* __restrict__ ctx){
  __shared__ unsigned short Ks[64][72];
  __shared__ unsigned short Vs[64][72];
  const int bx = blockIdx.x;
  const int qt = bx & 15;
  const int hd = (bx >> 4) & 15;
  const int n  = bx >> 8;
  const int q0 = qt * 64;
  const int tid  = threadIdx.x;
  const int lane = tid & 63;
  const int w    = tid >> 6;
  const int qrow = q0 + w * 16 + (lane >> 2);   // global s index of this lane's query
  const int dq   = (lane & 3) * 16;             // this lane's 16-dim slice
  const size_t headoff = (size_t)(n * NHEAD + hd) * S_LEN * DHEAD;

  const unsigned short* qp = qh + headoff + (size_t)qrow * DHEAD + dq;
  float qv[16];
  {
    bf16x8 a = *(const bf16x8*)qp;
    bf16x8 c = *(const bf16x8*)(qp + 8);
    #pragma unroll
    for (int i = 0; i < 8; i++){
      qv[i]     = bf2f((unsigned short)a[i]) * 0.125f;   // 1/sqrt(64)
      qv[8 + i] = bf2f((unsigned short)c[i]) * 0.125f;
    }
  }
  float m = -1e4f, lsum = 0.f;
  float oacc[16];
  #pragma unroll
  for (int i = 0; i < 16; i++) oacc[i] = 0.f;

  int t_first = q0 - WINR; if (t_first < 0) t_first = 0;        // q0 multiple of 64 -> aligned
  int t_last  = q0 + 63 + WINR; if (t_last > S_LEN - 1) t_last = S_LEN - 1;
  const unsigned short* kb = kh + headoff;
  const unsigned short* vb = vh + headoff;

  for (int tb = t_first; tb <= t_last; tb += 64){
    __syncthreads();
    #pragma unroll
    for (int pp = 0; pp < 2; pp++){
      int idx = pp * 256 + tid;
      int r = idx >> 3;
      int c = (idx & 7) * 8;
      *(bf16x8*)&Ks[r][c] = *(const bf16x8*)(kb + (size_t)(tb + r) * DHEAD + c);
      *(bf16x8*)&Vs[r][c] = *(const bf16x8*)(vb + (size_t)(tb + r) * DHEAD + c);
    }
    __syncthreads();
    for (int jj = 0; jj < 64; jj++){
      const int j = tb + jj;
      bf16x8 k0 = *(const bf16x8*)&Ks[jj][dq];
      bf16x8 k1 = *(const bf16x8*)&Ks[jj][dq + 8];
      float s = 0.f;
      #pragma unroll
      for (int i = 0; i < 8; i++) s += qv[i] * bf2f((unsigned short)k0[i]);
      #pragma unroll
      for (int i = 0; i < 8; i++) s += qv[8 + i] * bf2f((unsigned short)k1[i]);
      s += __shfl_xor(s, 1);
      s += __shfl_xor(s, 2);
      const bool inb = (j >= qrow - WINR) && (j <= qrow + WINR);
      s = inb ? s : -1e9f;
      const float nm = fmaxf(m, s);
      const float sc = __expf(m - nm);
      const float pe = __expf(s - nm);
      m = nm;
      lsum = lsum * sc + pe;
      bf16x8 v0 = *(const bf16x8*)&Vs[jj][dq];
      bf16x8 v1 = *(const bf16x8*)&Vs[jj][dq + 8];
      #pragma unroll
      for (int i = 0; i < 8; i++){
        oacc[i]     = oacc[i]     * sc + pe * bf2f((unsigned short)v0[i]);
        oacc[8 + i] = oacc[8 + i] * sc + pe * bf2f((unsigned short)v1[i]);
      }
    }
  }
  const float inv = 1.f / lsum;
  unsigned short* op = ctx + (size_t)(n * S_LEN + qrow) * DMODEL + hd * DHEAD + dq;
  bf16x8 o0, o1;
  #pragma unroll
  for (int i = 0; i < 8; i++){
    o0[i] = (short)f2bf(oacc[i] * inv);
    o1[i] = (short)f2bf(oacc[8 + i] * inv);
  }
  *(bf16x8*)op = o0;
  *(bf16x8*)(op + 8) = o1;
}

// ---------------- bf16 MFMA GEMM: C[M,N] = A[M,K] @ Bt[N,K]^T, fused epilogues -------
struct GemmP {
  const unsigned short* A;
  const unsigned short* Bt;
  int K;
  int N;
  const float* bias;
  const float* r0; const float* r1; const float* r2; const float* r3; // residual sources
  const unsigned short* aux;                                          // gate multiplier
  unsigned short* oq; unsigned short* ok; unsigned short* ov;         // qkv scatter
  unsigned short* ob;                                                 // bf16 out
  float* of;                                                          // f32 out
};

// MODE 0: qkv head scatter  1: +bias +residual(sel) -> f32
// MODE 2: silu -> bf16      3: aux * (acc+bias) -> bf16   4: +bias + r0 -> f32
template<int MODE>
__global__ __launch_bounds__(256) void gemm_bf16(GemmP p){
  __shared__ unsigned short As[128][40];   // +8 pad: fragment reads ~2-way (free)
  __shared__ unsigned short Bs[128][40];
  const int tid  = threadIdx.x;
  const int lane = tid & 63;
  const int w    = tid >> 6;
  const int wm   = (w >> 1) * 64;
  const int wn   = (w & 1) * 64;
  const int m0   = blockIdx.x * 128;
  const int n0   = blockIdx.y * 128;
  const int K    = p.K;
  const unsigned short* Ag = p.A  + (size_t)m0 * K;
  const unsigned short* Bg = p.Bt + (size_t)n0 * K;
  const int sr = tid >> 2;          // staging row 0..63 (and +64)
  const int sc = (tid & 3) * 8;     // staging k offset

  f32x4 acc[4][4];
  const f32x4 zero = {0.f, 0.f, 0.f, 0.f};
  #pragma unroll
  for (int i = 0; i < 4; i++)
    #pragma unroll
    for (int j = 0; j < 4; j++) acc[i][j] = zero;

  for (int k0 = 0; k0 < K; k0 += 32){
    __syncthreads();
    *(bf16x8*)&As[sr][sc]      = *(const bf16x8*)(Ag + (size_t)sr * K + k0 + sc);
    *(bf16x8*)&As[sr + 64][sc] = *(const bf16x8*)(Ag + (size_t)(sr + 64) * K + k0 + sc);
    *(bf16x8*)&Bs[sr][sc]      = *(const bf16x8*)(Bg + (size_t)sr * K + k0 + sc);
    *(bf16x8*)&Bs[sr + 64][sc] = *(const bf16x8*)(Bg + (size_t)(sr + 64) * K + k0 + sc);
    __syncthreads();
    bf16x8 af[4], bfr[4];
    #pragma unroll
    for (int i = 0; i < 4; i++){
      af[i]  = *(const bf16x8*)&As[wm + i * 16 + (lane & 15)][(lane >> 4) * 8];
      bfr[i] = *(const bf16x8*)&Bs[wn + i * 16 + (lane & 15)][(lane >> 4) * 8];
    }
    #pragma unroll
    for (int i = 0; i < 4; i++)
      #pragma unroll
      for (int j = 0; j < 4; j++)
        acc[i][j] = __builtin_amdgcn_mfma_f32_16x16x32_bf16(af[i], bfr[j], acc[i][j], 0, 0, 0);
  }

  const int rb = m0 + wm + ((lane >> 4) << 2);
  const int cb = n0 + wn + (lane & 15);
  #pragma unroll
  for (int i = 0; i < 4; i++){
    #pragma unroll
    for (int j = 0; j < 4; j++){
      const int col = cb + j * 16;
      const float bcol = p.bias[col];
      #pragma unroll
      for (int r = 0; r < 4; r++){
        const int row = rb + i * 16 + r;
        float v = acc[i][j][r] + bcol;
        if constexpr (MODE == 0){
          const int sect = col >> 10, c = col & 1023;
          const int hh = c >> 6, d = c & 63;
          const int nn = row >> 10, s = row & 1023;
          unsigned short* dst = (sect == 0) ? p.oq : (sect == 1) ? p.ok : p.ov;
          dst[((size_t)(nn * NHEAD + hh) * S_LEN + s) * DHEAD + d] = f2bf(v);
        } else if constexpr (MODE == 1){
          const float* rs = (row < 2048) ? p.r0 : (row < 4096) ? p.r1 : (row < 6144) ? p.r2 : p.r3;
          p.of[(size_t)row * DMODEL + col] = v + rs[(size_t)(row & 2047) * DMODEL + col];
        } else if constexpr (MODE == 2){
          const float sv = v / (1.f + __expf(-v));
          p.ob[(size_t)row * p.N + col] = f2bf(sv);
        } else if constexpr (MODE == 3){
          const float a = bf2f(p.aux[(size_t)row * p.N + col]);
          p.ob[(size_t)row * p.N + col] = f2bf(a * v);
        } else {
          p.of[(size_t)row * DMODEL + col] = v + p.r0[(size_t)row * DMODEL + col];
        }
      }
    }
  }
}

// ------------------------------------------------------------------------------------
extern "C" void kernel_launch(void* const* d_in, const int* in_sizes, int n_in,
                              void* d_out, int out_size, void* d_ws, size_t ws_size,
                              hipStream_t stream){
  const float* fin  = (const float*)d_in[0];
  const float* vis  = (const float*)d_in[1];
  const float* txt  = (const float*)d_in[2];
  const float* aud  = (const float*)d_in[3];
  const float* ln1g = (const float*)d_in[4];
  const float* ln1b = (const float*)d_in[5];
  const float* Wqkv = (const float*)d_in[6];
  const float* bqkv = (const float*)d_in[7];
  const float* Wo   = (const float*)d_in[8];
  const float* bo   = (const float*)d_in[9];
  const float* ln2g = (const float*)d_in[10];
  const float* ln2b = (const float*)d_in[11];
  const float* W1   = (const float*)d_in[12];
  const float* b1   = (const float*)d_in[13];
  const float* W2   = (const float*)d_in[14];
  const float* b2   = (const float*)d_in[15];
  const float* W3   = (const float*)d_in[16];
  const float* b3   = (const float*)d_in[17];

  char* ws = (char*)d_ws;
  // layout (bytes)
  unsigned short* Wqkv_t = (unsigned short*)(ws + 0);          //  6,291,456
  unsigned short* Wo_t   = (unsigned short*)(ws + 6291456);    //  2,097,152
  unsigned short* W1t    = (unsigned short*)(ws + 8388608);    //  8,388,608
  unsigned short* W2t    = (unsigned short*)(ws + 16777216);   //  8,388,608
  unsigned short* W3t    = (unsigned short*)(ws + 25165824);   //  8,388,608
  unsigned short* h      = (unsigned short*)(ws + 33554432);   // 16,777,216 (h1 then h2)
  unsigned short* qh     = (unsigned short*)(ws + 50331648);   // 16,777,216
  unsigned short* kh     = (unsigned short*)(ws + 67108864);   // 16,777,216
  unsigned short* vh     = (unsigned short*)(ws + 83886080);   // 16,777,216
  unsigned short* ctx    = (unsigned short*)(ws + 100663296);  // 16,777,216
  float*          x1     = (float*)(ws + 117440512);           // 33,554,432  (ends 150,994,944)
  unsigned short* t1     = qh;  // [8192][4096] bf16, aliases qh..ctx (dead by then)

  // 1) weight transposes -> bf16 [N][K]
  transpose_w<<<dim3(3072/32, 1024/32), 256, 0, stream>>>(Wqkv, Wqkv_t, 1024, 3072);
  transpose_w<<<dim3(1024/32, 1024/32), 256, 0, stream>>>(Wo,   Wo_t,   1024, 1024);
  transpose_w<<<dim3(4096/32, 1024/32), 256, 0, stream>>>(W1,   W1t,    1024, 4096);
  transpose_w<<<dim3(4096/32, 1024/32), 256, 0, stream>>>(W2,   W2t,    1024, 4096);
  transpose_w<<<dim3(1024/32, 4096/32), 256, 0, stream>>>(W3,   W3t,    4096, 1024);

  // 2) LN1
  ln_kernel<<<MROWS, 256, 0, stream>>>(fin, vis, txt, aud, ln1g, ln1b, h);

  // 3) QKV GEMM (M=8192, N=3072, K=1024) with head scatter
  {
    GemmP p{};
    p.A = h; p.Bt = Wqkv_t; p.K = 1024; p.N = 3072; p.bias = bqkv;
    p.oq = qh; p.ok = kh; p.ov = vh;
    gemm_bf16<0><<<dim3(64, 24), 256, 0, stream>>>(p);
  }

  // 4) banded attention -> ctx
  attn_kernel<<<2048, 256, 0, stream>>>(qh, kh, vh, ctx);

  // 5) output projection + residual -> x1 f32
  {
    GemmP p{};
    p.A = ctx; p.Bt = Wo_t; p.K = 1024; p.N = 1024; p.bias = bo;
    p.r0 = fin; p.r1 = vis; p.r2 = txt; p.r3 = aud;
    p.of = x1;
    gemm_bf16<1><<<dim3(64, 8), 256, 0, stream>>>(p);
  }

  // 6) LN2
  ln_kernel<<<MROWS, 256, 0, stream>>>(x1, x1 + (size_t)2048 * 1024, x1 + (size_t)4096 * 1024,
                                       x1 + (size_t)6144 * 1024, ln2g, ln2b, h);

  // 7) FFN up (silu branch) -> t1 bf16
  {
    GemmP p{};
    p.A = h; p.Bt = W1t; p.K = 1024; p.N = HIDDIM; p.bias = b1;
    p.ob = t1;
    gemm_bf16<2><<<dim3(64, 32), 256, 0, stream>>>(p);
  }

  // 8) FFN up (gate branch), multiply in-place -> t1 bf16
  {
    GemmP p{};
    p.A = h; p.Bt = W2t; p.K = 1024; p.N = HIDDIM; p.bias = b2;
    p.aux = t1; p.ob = t1;
    gemm_bf16<3><<<dim3(64, 32), 256, 0, stream>>>(p);
  }

  // 9) FFN down + residual -> d_out f32
  {
    GemmP p{};
    p.A = t1; p.Bt = W3t; p.K = HIDDIM; p.N = 1024; p.bias = b3;
    p.r0 = x1;
    p.of = (float*)d_out;
    gemm_bf16<4><<<dim3(64, 8), 256, 0, stream>>>(p);
  }

  (void)in_sizes; (void)n_in; (void)out_size; (void)ws_size;
}

// Round 2
// 551.218 us; speedup vs baseline: 1.5903x; 1.5903x over previous
//
#include <hip/hip_runtime.h>

#define S_LEN  1024
#define DMODEL 1024
#define NHEAD  16
#define DHEAD  64
#define MROWS  8192   // 8 sequences * 1024
#define HIDDIM 4096
#define WINR   128

typedef __attribute__((ext_vector_type(8))) short bf16x8;
typedef __attribute__((ext_vector_type(4))) float f32x4;

__device__ __forceinline__ float bf2f(unsigned short u){ return __uint_as_float(((unsigned)u) << 16); }
__device__ __forceinline__ unsigned short f2bf(float f){
  unsigned u = __float_as_uint(f);
  u += 0x7FFFu + ((u >> 16) & 1u);
  return (unsigned short)(u >> 16);
}

// async global->LDS, 16 B per lane; lds dest must be wave-uniform base (lane-linear fill)
__device__ __forceinline__ void gload_lds16(const unsigned short* g, unsigned short* l){
  __builtin_amdgcn_global_load_lds((const __attribute__((address_space(1))) unsigned int*)g,
                                   (__attribute__((address_space(3))) unsigned int*)l, 16, 0, 0);
}

// ---------------- weight transpose: in f32 [R][C] -> out bf16 [C][R] ----------------
__global__ __launch_bounds__(256) void transpose_w(const float* __restrict__ in,
                                                   unsigned short* __restrict__ out,
                                                   int R, int C){
  __shared__ float tile[32][33];
  const int c0 = blockIdx.x * 32;
  const int r0 = blockIdx.y * 32;
  const int tx = threadIdx.x & 31;
  const int ty = threadIdx.x >> 5;   // 0..7
  #pragma unroll
  for (int i = 0; i < 32; i += 8)
    tile[ty + i][tx] = in[(size_t)(r0 + ty + i) * C + c0 + tx];
  __syncthreads();
  #pragma unroll
  for (int i = 0; i < 32; i += 8)
    out[(size_t)(c0 + ty + i) * R + r0 + tx] = f2bf(tile[tx][ty + i]);
}

// ---------------- LayerNorm: row per block, 4 source pointers (2048 rows each) -------
__global__ __launch_bounds__(256) void ln_kernel(const float* __restrict__ s0, const float* __restrict__ s1,
                                                 const float* __restrict__ s2, const float* __restrict__ s3,
                                                 const float* __restrict__ g, const float* __restrict__ b,
                                                 unsigned short* __restrict__ out){
  const int row = blockIdx.x;
  const int t = threadIdx.x;
  const float* src = (row < 2048) ? s0 : (row < 4096) ? s1 : (row < 6144) ? s2 : s3;
  const float* x = src + (size_t)(row & 2047) * DMODEL;
  float4 v = *(const float4*)&x[t * 4];
  float sum  = v.x + v.y + v.z + v.w;
  float ssum = v.x*v.x + v.y*v.y + v.z*v.z + v.w*v.w;
  #pragma unroll
  for (int o = 32; o > 0; o >>= 1){
    sum  += __shfl_down(sum, o);
    ssum += __shfl_down(ssum, o);
  }
  __shared__ float red[8];
  if ((t & 63) == 0){ red[t >> 6] = sum; red[4 + (t >> 6)] = ssum; }
  __syncthreads();
  sum  = red[0] + red[1] + red[2] + red[3];
  ssum = red[4] + red[5] + red[6] + red[7];
  const float mu  = sum * (1.f / DMODEL);
  const float var = ssum * (1.f / DMODEL) - mu * mu;
  const float rs  = rsqrtf(var + 1e-5f);
  float4 gg = *(const float4*)&g[t * 4];
  float4 bb = *(const float4*)&b[t * 4];
  ushort4 o;
  o.x = f2bf((v.x - mu) * rs * gg.x + bb.x);
  o.y = f2bf((v.y - mu) * rs * gg.y + bb.y);
  o.z = f2bf((v.z - mu) * rs * gg.z + bb.z);
  o.w = f2bf((v.w - mu) * rs * gg.w + bb.w);
  *(ushort4*)&out[(size_t)row * DMODEL + t * 4] = o;
}

// ---------------- banded flash attention, MFMA 16x16x32, swapped QK^T ----------------
// grid: n(8)*head(16)*qtile(16); block 256 = 4 waves, wave w -> queries q0+w*16..+15
// K, V^T tiles staged via global_load_lds with XOR-swizzled SOURCE (linear LDS dest);
// fragment ds_read_b128 applies the same XOR -> ~2-way banks (free).
__global__ __launch_bounds__(256) void attn_kernel(const unsigned short* __restrict__ qh,
                                                   const unsigned short* __restrict__ kh,
                                                   const unsigned short* __restrict__ vt,
                                                   unsigned short* __restrict__ ctx){
  __shared__ unsigned short Ks[64 * 64];      // [key][d]  (d XOR-swizzled by key&7)
  __shared__ unsigned short Vs[64 * 64];      // [d][key]  (key XOR-swizzled by d&7)
  __shared__ unsigned short Ps[4][16 * 64];   // per-wave P [q][key] (key XOR by q&7)
  const int bx = blockIdx.x;
  const int qt = bx & 15, hd = (bx >> 4) & 15, n = bx >> 8;
  const int q0 = qt * 64;
  const int tid = threadIdx.x, lane = tid & 63, w = tid >> 6;
  const int hi = lane >> 4, lo = lane & 15;
  const size_t headoff = (size_t)(n * NHEAD + hd) * S_LEN * DHEAD;
  const unsigned short* kb = kh + headoff;
  const unsigned short* vb = vt + headoff;    // [64 d][1024 s]

  // Q fragments (Bt operand); this lane's query = q0 + w*16 + lo
  const int qg = q0 + w * 16 + lo;
  bf16x8 bq0 = *(const bf16x8*)(qh + headoff + (size_t)qg * DHEAD + hi * 8);
  bf16x8 bq1 = *(const bf16x8*)(qh + headoff + (size_t)qg * DHEAD + 32 + hi * 8);

  f32x4 oa[4];
  const f32x4 zero = {0.f, 0.f, 0.f, 0.f};
  #pragma unroll
  for (int dj = 0; dj < 4; dj++) oa[dj] = zero;
  float m = -20.f, lsum = 0.f;

  int t_first = q0 - WINR; if (t_first < 0) t_first = 0;
  int t_last  = q0 + 63 + WINR; if (t_last > S_LEN - 1) t_last = S_LEN - 1;

  const int sk = ((lane & 7) ^ (lane >> 3)) * 8;   // swizzled source k-chunk (elements)
  const int px = (lo & 7) * 8;                     // read-side XOR for rows with row&7 == lo&7

  for (int tb = t_first; tb <= t_last; tb += 64){
    __syncthreads();
    #pragma unroll
    for (int p = 0; p < 2; p++){
      const int r = w * 16 + p * 8 + (lane >> 3);  // r&7 == lane>>3
      gload_lds16(kb + (size_t)(tb + r) * DHEAD + sk, Ks + (w * 16 + p * 8) * 64);
      gload_lds16(vb + (size_t)r * S_LEN + tb + sk, Vs + (w * 16 + p * 8) * 64);
    }
    __syncthreads();

    // QK^T (swapped): S^T[key][query], A = K rows, Bt = Q rows
    f32x4 sc[4];
    #pragma unroll
    for (int j = 0; j < 4; j++){
      const int row = j * 16 + lo;
      bf16x8 ak0 = *(const bf16x8*)&Ks[row * 64 + ((hi * 8) ^ px)];
      bf16x8 ak1 = *(const bf16x8*)&Ks[row * 64 + ((32 + hi * 8) ^ px)];
      sc[j] = __builtin_amdgcn_mfma_f32_16x16x32_bf16(ak0, bq0, zero, 0, 0, 0);
      sc[j] = __builtin_amdgcn_mfma_f32_16x16x32_bf16(ak1, bq1, sc[j], 0, 0, 0);
    }

    // mask + scale + online softmax (state per lane: query lo, replicated over hi groups)
    float mloc = -1e30f;
    #pragma unroll
    for (int j = 0; j < 4; j++)
      #pragma unroll
      for (int r = 0; r < 4; r++){
        const int key = tb + j * 16 + hi * 4 + r;
        float s = sc[j][r] * 0.125f;
        s = ((unsigned)(key - qg + WINR) <= 2u * WINR) ? s : -1e9f;
        sc[j][r] = s;
        mloc = fmaxf(mloc, s);
      }
    mloc = fmaxf(mloc, __shfl_xor(mloc, 16));
    mloc = fmaxf(mloc, __shfl_xor(mloc, 32));
    const float nm = fmaxf(m, mloc);
    const float scale = __expf(m - nm);
    m = nm;
    float psum = 0.f;
    #pragma unroll
    for (int j = 0; j < 4; j++){
      float p0 = __expf(sc[j][0] - nm), p1 = __expf(sc[j][1] - nm);
      float p2 = __expf(sc[j][2] - nm), p3 = __expf(sc[j][3] - nm);
      psum += (p0 + p1) + (p2 + p3);
      ushort4 pw = { f2bf(p0), f2bf(p1), f2bf(p2), f2bf(p3) };
      *(ushort4*)&Ps[w][lo * 64 + ((hi * 4 + 16 * j) ^ px)] = pw;
    }
    psum += __shfl_xor(psum, 16);
    psum += __shfl_xor(psum, 32);
    lsum = lsum * scale + psum;

    // rescale O (O rows = local query hi*4+r); scale lives at lane with lo == that query
    float scr[4];
    #pragma unroll
    for (int r = 0; r < 4; r++) scr[r] = __shfl(scale, (lane & 48) + hi * 4 + r);
    #pragma unroll
    for (int dj = 0; dj < 4; dj++)
      #pragma unroll
      for (int r = 0; r < 4; r++) oa[dj][r] *= scr[r];

    // PV: A = P[q][k], Bt = V^T[d][k]
    bf16x8 pa0 = *(const bf16x8*)&Ps[w][lo * 64 + ((hi * 8) ^ px)];
    bf16x8 pa1 = *(const bf16x8*)&Ps[w][lo * 64 + ((32 + hi * 8) ^ px)];
    #pragma unroll
    for (int dj = 0; dj < 4; dj++){
      const int dr = dj * 16 + lo;
      bf16x8 bv0 = *(const bf16x8*)&Vs[dr * 64 + ((hi * 8) ^ px)];
      bf16x8 bv1 = *(const bf16x8*)&Vs[dr * 64 + ((32 + hi * 8) ^ px)];
      oa[dj] = __builtin_amdgcn_mfma_f32_16x16x32_bf16(pa0, bv0, oa[dj], 0, 0, 0);
      oa[dj] = __builtin_amdgcn_mfma_f32_16x16x32_bf16(pa1, bv1, oa[dj], 0, 0, 0);
    }
  }

  const float inv = 1.f / lsum;
  float invr[4];
  #pragma unroll
  for (int r = 0; r < 4; r++) invr[r] = __shfl(inv, (lane & 48) + hi * 4 + r);
  #pragma unroll
  for (int dj = 0; dj < 4; dj++)
    #pragma unroll
    for (int r = 0; r < 4; r++){
      const int srow = q0 + w * 16 + hi * 4 + r;
      ctx[((size_t)(n * S_LEN + srow)) * DMODEL + hd * DHEAD + dj * 16 + lo] =
          f2bf(oa[dj][r] * invr[r]);
    }
}

// ---------------- bf16 MFMA GEMM (m97 structure): C = A @ Bt^T, fused epilogues ------
struct GemmP {
  const unsigned short* A;
  const unsigned short* Bt;
  int K;
  int N;
  const float* bias;
  const float* r0; const float* r1; const float* r2; const float* r3; // residual sources
  const unsigned short* aux;                                          // gate multiplier
  unsigned short* oq; unsigned short* ok; unsigned short* ov;         // qkv scatter (ov = V^T)
  unsigned short* ob;                                                 // bf16 out
  float* of;                                                          // f32 out
};

// MODE 0: qkv head scatter (V transposed)  1: +bias +residual(sel) -> f32
// MODE 2: silu -> bf16      3: aux * (acc+bias) -> bf16   4: +bias + r0 -> f32
template<int MODE>
__global__ __launch_bounds__(256) void gemm_bf16(GemmP p){
  __shared__ unsigned short As[128 * 32];   // linear: global_load_lds dest
  __shared__ unsigned short Bs[128 * 32];
  const int tid  = threadIdx.x;
  const int lane = tid & 63;
  const int w    = tid >> 6;
  const int wm   = (w >> 1) * 64;
  const int wn   = (w & 1) * 64;
  const int m0   = blockIdx.x * 128;
  const int n0   = blockIdx.y * 128;
  const int K    = p.K;
  const unsigned short* Ag = p.A  + (size_t)m0 * K;
  const unsigned short* Bg = p.Bt + (size_t)n0 * K;
  const int lr = lane >> 2;          // staging sub-row 0..15
  const int lc = (lane & 3) * 8;     // staging k offset (elements)

  f32x4 acc[4][4];
  const f32x4 zero = {0.f, 0.f, 0.f, 0.f};
  #pragma unroll
  for (int i = 0; i < 4; i++)
    #pragma unroll
    for (int j = 0; j < 4; j++) acc[i][j] = zero;

  for (int k0 = 0; k0 < K; k0 += 32){
    __syncthreads();
    #pragma unroll
    for (int pp = 0; pp < 2; pp++){
      const int rb = (w * 2 + pp) * 16;
      gload_lds16(Ag + (size_t)(rb + lr) * K + k0 + lc, As + rb * 32);
      gload_lds16(Bg + (size_t)(rb + lr) * K + k0 + lc, Bs + rb * 32);
    }
    __syncthreads();
    bf16x8 af[4], bfr[4];
    #pragma unroll
    for (int i = 0; i < 4; i++){
      af[i]  = *(const bf16x8*)&As[(wm + i * 16 + (lane & 15)) * 32 + (lane >> 4) * 8];
      bfr[i] = *(const bf16x8*)&Bs[(wn + i * 16 + (lane & 15)) * 32 + (lane >> 4) * 8];
    }
    #pragma unroll
    for (int i = 0; i < 4; i++)
      #pragma unroll
      for (int j = 0; j < 4; j++)
        acc[i][j] = __builtin_amdgcn_mfma_f32_16x16x32_bf16(af[i], bfr[j], acc[i][j], 0, 0, 0);
  }

  const int rb = m0 + wm + ((lane >> 4) << 2);
  const int cb = n0 + wn + (lane & 15);
  #pragma unroll
  for (int i = 0; i < 4; i++){
    #pragma unroll
    for (int j = 0; j < 4; j++){
      const int col = cb + j * 16;
      const float bcol = p.bias[col];
      #pragma unroll
      for (int r = 0; r < 4; r++){
        const int row = rb + i * 16 + r;
        float v = acc[i][j][r] + bcol;
        if constexpr (MODE == 0){
          const int sect = col >> 10, c = col & 1023;
          const int hh = c >> 6, d = c & 63;
          const int nn = row >> 10, s = row & 1023;
          if (sect == 2)
            p.ov[((size_t)(nn * NHEAD + hh) * DHEAD + d) * S_LEN + s] = f2bf(v);  // V^T
          else {
            unsigned short* dst = sect ? p.ok : p.oq;
            dst[((size_t)(nn * NHEAD + hh) * S_LEN + s) * DHEAD + d] = f2bf(v);
          }
        } else if constexpr (MODE == 1){
          const float* rs = (row < 2048) ? p.r0 : (row < 4096) ? p.r1 : (row < 6144) ? p.r2 : p.r3;
          p.of[(size_t)row * DMODEL + col] = v + rs[(size_t)(row & 2047) * DMODEL + col];
        } else if constexpr (MODE == 2){
          const float sv = v / (1.f + __expf(-v));
          p.ob[(size_t)row * p.N + col] = f2bf(sv);
        } else if constexpr (MODE == 3){
          const float a = bf2f(p.aux[(size_t)row * p.N + col]);
          p.ob[(size_t)row * p.N + col] = f2bf(a * v);
        } else {
          p.of[(size_t)row * DMODEL + col] = v + p.r0[(size_t)row * DMODEL + col];
        }
      }
    }
  }
}

// ------------------------------------------------------------------------------------
extern "C" void kernel_launch(void* const* d_in, const int* in_sizes, int n_in,
                              void* d_out, int out_size, void* d_ws, size_t ws_size,
                              hipStream_t stream){
  const float* fin  = (const float*)d_in[0];
  const float* vis  = (const float*)d_in[1];
  const float* txt  = (const float*)d_in[2];
  const float* aud  = (const float*)d_in[3];
  const float* ln1g = (const float*)d_in[4];
  const float* ln1b = (const float*)d_in[5];
  const float* Wqkv = (const float*)d_in[6];
  const float* bqkv = (const float*)d_in[7];
  const float* Wo   = (const float*)d_in[8];
  const float* bo   = (const float*)d_in[9];
  const float* ln2g = (const float*)d_in[10];
  const float* ln2b = (const float*)d_in[11];
  const float* W1   = (const float*)d_in[12];
  const float* b1   = (const float*)d_in[13];
  const float* W2   = (const float*)d_in[14];
  const float* b2   = (const float*)d_in[15];
  const float* W3   = (const float*)d_in[16];
  const float* b3   = (const float*)d_in[17];

  char* ws = (char*)d_ws;
  unsigned short* Wqkv_t = (unsigned short*)(ws + 0);          //  6,291,456
  unsigned short* Wo_t   = (unsigned short*)(ws + 6291456);    //  2,097,152
  unsigned short* W1t    = (unsigned short*)(ws + 8388608);    //  8,388,608
  unsigned short* W2t    = (unsigned short*)(ws + 16777216);   //  8,388,608
  unsigned short* W3t    = (unsigned short*)(ws + 25165824);   //  8,388,608
  unsigned short* h      = (unsigned short*)(ws + 33554432);   // 16,777,216
  unsigned short* qh     = (unsigned short*)(ws + 50331648);   // 16,777,216
  unsigned short* kh     = (unsigned short*)(ws + 67108864);   // 16,777,216
  unsigned short* vhT    = (unsigned short*)(ws + 83886080);   // 16,777,216  [n*h][64][1024]
  unsigned short* ctx    = (unsigned short*)(ws + 100663296);  // 16,777,216
  float*          x1     = (float*)(ws + 117440512);           // 33,554,432 (ends 150,994,944)
  unsigned short* t1     = qh;  // [8192][4096] bf16, aliases qh..ctx (dead by step 7)

  // 1) weight transposes -> bf16 [N][K]
  transpose_w<<<dim3(3072/32, 1024/32), 256, 0, stream>>>(Wqkv, Wqkv_t, 1024, 3072);
  transpose_w<<<dim3(1024/32, 1024/32), 256, 0, stream>>>(Wo,   Wo_t,   1024, 1024);
  transpose_w<<<dim3(4096/32, 1024/32), 256, 0, stream>>>(W1,   W1t,    1024, 4096);
  transpose_w<<<dim3(4096/32, 1024/32), 256, 0, stream>>>(W2,   W2t,    1024, 4096);
  transpose_w<<<dim3(1024/32, 4096/32), 256, 0, stream>>>(W3,   W3t,    4096, 1024);

  // 2) LN1
  ln_kernel<<<MROWS, 256, 0, stream>>>(fin, vis, txt, aud, ln1g, ln1b, h);

  // 3) QKV GEMM (M=8192, N=3072, K=1024), head scatter, V transposed
  {
    GemmP p{};
    p.A = h; p.Bt = Wqkv_t; p.K = 1024; p.N = 3072; p.bias = bqkv;
    p.oq = qh; p.ok = kh; p.ov = vhT;
    gemm_bf16<0><<<dim3(64, 24), 256, 0, stream>>>(p);
  }

  // 4) banded MFMA attention -> ctx
  attn_kernel<<<2048, 256, 0, stream>>>(qh, kh, vhT, ctx);

  // 5) output projection + residual -> x1 f32
  {
    GemmP p{};
    p.A = ctx; p.Bt = Wo_t; p.K = 1024; p.N = 1024; p.bias = bo;
    p.r0 = fin; p.r1 = vis; p.r2 = txt; p.r3 = aud;
    p.of = x1;
    gemm_bf16<1><<<dim3(64, 8), 256, 0, stream>>>(p);
  }

  // 6) LN2
  ln_kernel<<<MROWS, 256, 0, stream>>>(x1, x1 + (size_t)2048 * 1024, x1 + (size_t)4096 * 1024,
                                       x1 + (size_t)6144 * 1024, ln2g, ln2b, h);

  // 7) FFN up (silu branch) -> t1 bf16
  {
    GemmP p{};
    p.A = h; p.Bt = W1t; p.K = 1024; p.N = HIDDIM; p.bias = b1;
    p.ob = t1;
    gemm_bf16<2><<<dim3(64, 32), 256, 0, stream>>>(p);
  }

  // 8) FFN up (gate branch), multiply in-place -> t1 bf16
  {
    GemmP p{};
    p.A = h; p.Bt = W2t; p.K = 1024; p.N = HIDDIM; p.bias = b2;
    p.aux = t1; p.ob = t1;
    gemm_bf16<3><<<dim3(64, 32), 256, 0, stream>>>(p);
  }

  // 9) FFN down + residual -> d_out f32
  {
    GemmP p{};
    p.A = t1; p.Bt = W3t; p.K = HIDDIM; p.N = 1024; p.bias = b3;
    p.r0 = x1;
    p.of = (float*)d_out;
    gemm_bf16<4><<<dim3(64, 8), 256, 0, stream>>>(p);
  }

  (void)in_sizes; (void)n_in; (void)out_size; (void)ws_size;
}